// Round 2
// baseline (303.054 us; speedup 1.0000x reference)
//
#include <hip/hip_runtime.h>
#include <hip/hip_bf16.h>

// Word embedding gather: out[t, :] = weight[ids[t], :]
// weight: [50257, 1024] fp32, ids: [16*2048] int32, out: [32768, 1024] fp32.
// Memory-bound. Round 1 (1 token/block, 1 load/thread) hit only 0.9 TB/s —
// latency-bound: single outstanding load per lane + 32768 tiny blocks.
// Round 2: 8 tokens per block -> 8 independent 16B loads in flight per lane,
// indices are workgroup-uniform (scalar loads), 4096 longer-lived blocks.

#define DIM 1024
#define ROWV (DIM / 4)        // 256 float4 per row
#define TOK_PER_BLOCK 8

__global__ __launch_bounds__(256) void WordEmbedding_kernel(
    const float4* __restrict__ weight,
    const int* __restrict__ ids,
    float4* __restrict__ out) {
    const int t0 = blockIdx.x * TOK_PER_BLOCK;
    const int tid = threadIdx.x;

    // Workgroup-uniform index loads -> scalar s_load_dwordx4 pair
    int idx[TOK_PER_BLOCK];
#pragma unroll
    for (int k = 0; k < TOK_PER_BLOCK; ++k) idx[k] = ids[t0 + k];

    // 8 independent gathered row-segment loads in flight per lane
    float4 v[TOK_PER_BLOCK];
#pragma unroll
    for (int k = 0; k < TOK_PER_BLOCK; ++k)
        v[k] = weight[(size_t)idx[k] * ROWV + tid];

    // Coalesced stores
#pragma unroll
    for (int k = 0; k < TOK_PER_BLOCK; ++k)
        out[(size_t)(t0 + k) * ROWV + tid] = v[k];
}

extern "C" void kernel_launch(void* const* d_in, const int* in_sizes, int n_in,
                              void* d_out, int out_size, void* d_ws, size_t ws_size,
                              hipStream_t stream) {
    const float4* weight = (const float4*)d_in[0];
    const int* ids = (const int*)d_in[1];
    float4* out = (float4*)d_out;
    const int n_tokens = in_sizes[1];  // 32768, divisible by TOK_PER_BLOCK
    WordEmbedding_kernel<<<n_tokens / TOK_PER_BLOCK, ROWV, 0, stream>>>(
        weight, ids, out);
}

// Round 4
// 300.356 us; speedup vs baseline: 1.0090x; 1.0090x over previous
//
#include <hip/hip_runtime.h>
#include <hip/hip_bf16.h>

// Word embedding gather: out[t, :] = weight[ids[t], :]
// weight: [50257, 1024] fp32 (206 MB), ids: [16*2048] int32, out: 134 MB fp32.
// Round 1: 1 token/block -> bench 300 us. Round 2: 8 tok/block -> 303 us
// (neutral: GPU-wide MLP already saturated with 32768 blocks).
// Round 3/4 theory: output stores thrash the 256 MB L3 that should be caching
// the 206 MB weight table -> gather reads fall to HBM random access.
// Use nontemporal stores for the (never re-read) output to preserve L3.
// (Round 3 failed to compile: the builtin needs a native vector type, not
// HIP's float4 class -> use ext_vector_type(4).)

#define DIM 1024
#define ROWV (DIM / 4)        // 256 16B-vectors per row
#define TOK_PER_BLOCK 8

typedef float fvec4 __attribute__((ext_vector_type(4)));

__global__ __launch_bounds__(256) void WordEmbedding_kernel(
    const fvec4* __restrict__ weight,
    const int* __restrict__ ids,
    fvec4* __restrict__ out) {
    const int t0 = blockIdx.x * TOK_PER_BLOCK;
    const int tid = threadIdx.x;

    int idx[TOK_PER_BLOCK];
#pragma unroll
    for (int k = 0; k < TOK_PER_BLOCK; ++k) idx[k] = ids[t0 + k];

    fvec4 v[TOK_PER_BLOCK];
#pragma unroll
    for (int k = 0; k < TOK_PER_BLOCK; ++k)
        v[k] = weight[(size_t)idx[k] * ROWV + tid];

#pragma unroll
    for (int k = 0; k < TOK_PER_BLOCK; ++k) {
        fvec4* dst = out + (size_t)(t0 + k) * ROWV + tid;
        __builtin_nontemporal_store(v[k], dst);
    }
}

extern "C" void kernel_launch(void* const* d_in, const int* in_sizes, int n_in,
                              void* d_out, int out_size, void* d_ws, size_t ws_size,
                              hipStream_t stream) {
    const fvec4* weight = (const fvec4*)d_in[0];
    const int* ids = (const int*)d_in[1];
    fvec4* out = (fvec4*)d_out;
    const int n_tokens = in_sizes[1];  // 32768, divisible by TOK_PER_BLOCK
    WordEmbedding_kernel<<<n_tokens / TOK_PER_BLOCK, ROWV, 0, stream>>>(
        weight, ids, out);
}